// Round 14
// baseline (64.301 us; speedup 1.0000x reference)
//
#include <hip/hip_runtime.h>

// ---------- types ----------
typedef __attribute__((ext_vector_type(8))) short bf16x8;
typedef __attribute__((ext_vector_type(4))) float f32x4;
typedef __attribute__((ext_vector_type(16))) float f32x16;

__device__ __forceinline__ short f2bf(float f) {
  unsigned u = __builtin_bit_cast(unsigned, f);
  u += 0x7fffu + ((u >> 16) & 1u);   // round-to-nearest-even
  return (short)(u >> 16);
}

// ---------- layout ----------
// IN=4096, OUT=4096, RANK=1024, GROUP=128, PACK=8
// GEMM: out[n*4096+m] = sum_r W_V(m,r)*S(r) * W_U(r,n)
// 32x32x16 MFMA fragment-major storage (verified R12/R13); each 1 KB block =
// one fragment in lane order (lane*16B). A/B map: row=lane&31, k=(lane>>5)*8+e.
// A: elem addr = ((mp*32+kt)*8  + mi*2+kk)*512 + lane*8 + e
//   m = mp*128 + mi*32 + (lane&31); r = kt*32 + kk*16 + (lane>>5)*8 + e
// B: elem addr = ((np*32+kt)*16 + nj*2+kk)*512 + lane*8 + e
//   n = np*256 + nj*32 + (lane&31); r = kt*32 + kk*16 + (lane>>5)*8 + e

// ---------- stage 1: fused dequant (V -> A, U -> B) ----------
__global__ __launch_bounds__(256) void dequant_fused(
    const int* __restrict__ qw_V, const int* __restrict__ qz_V,
    const float* __restrict__ sc_V, const float* __restrict__ S,
    short* __restrict__ A,
    const int* __restrict__ qw_U, const int* __restrict__ qz_U,
    const float* __restrict__ sc_U, short* __restrict__ B) {
  const int bid = blockIdx.x;
  if (bid < 2048) {
    const int t    = bid * 256 + threadIdx.x;      // 0..524287
    const int tile = t >> 9;                       // mp*32 + kt
    const int blk  = (t >> 6) & 7;                 // mi*2 + kk
    const int lane = t & 63;
    const int m  = (tile >> 5) * 128 + (blk >> 1) * 32 + (lane & 31);
    const int r0 = (tile & 31) * 32 + (blk & 1) * 16 + ((lane >> 5) << 3);
    const int g  = m >> 7;
    const int sh = (m & 7) << 2;
    const int zw = qz_V[(g << 7) + (r0 >> 3)];
    const int*   wq  = qw_V + (m >> 3) * 1024 + r0;
    const float* scp = sc_V + (g << 10) + r0;
    const float* sp  = S + r0;
    bf16x8 res;
#pragma unroll
    for (int e = 0; e < 8; ++e) {
      int q = (wq[e] >> sh) & 15;
      int z = ((zw >> (e << 2)) & 15) + 1;
      res[e] = f2bf((float)(q - z) * scp[e] * sp[e]);
    }
    *(bf16x8*)(A + ((size_t)t << 3)) = res;        // coalesced
  } else {
    const int t    = (bid - 2048) * 256 + threadIdx.x;
    const int tile = t >> 10;                      // np*32 + kt
    const int blk  = (t >> 6) & 15;                // nj*2 + kk
    const int lane = t & 63;
    const int n  = (tile >> 5) * 256 + (blk >> 1) * 32 + (lane & 31);
    const int r0 = (tile & 31) * 32 + (blk & 1) * 16 + ((lane >> 5) << 3);
    const int w  = qw_U[(r0 >> 3) * 4096 + n];
    const int g  = r0 >> 7;
    const int zw = qz_U[(g << 9) + (n >> 3)];
    const int z  = ((zw >> ((n & 7) << 2)) & 15) + 1;
    const float s = sc_U[(g << 12) + n];
    bf16x8 res;
#pragma unroll
    for (int e = 0; e < 8; ++e) {
      int q = (w >> (e << 2)) & 15;
      res[e] = f2bf((float)(q - z) * s);
    }
    *(bf16x8*)(B + ((size_t)t << 3)) = res;
  }
}

// ---------- stage 2: direct-to-register GEMM (no LDS, no barriers) ----------
// 4 waves/block; wave tile 64(m) x 128(n) = acc[2][4] f32x16 (128 VGPR).
// Per K-step: 12 global_load_dwordx4 straight to regs (fragment-major makes
// each lane's slice contiguous), 16 MFMA 32x32x16. Ping-pong reg buffers,
// statically indexed (rule #20). Compiler inserts counted vmcnt on the
// load->MFMA deps. 512 blocks x 4 waves = 2048 waves = 8 waves/CU exact fill.
// Duplication: A frag read by 2 waves (wn), B frag by 2 waves (wm) -> L1/L2
// absorb; total reg-load traffic ~786 MB, L2-resident panels via XCD swizzle.
__global__ __launch_bounds__(256, 2) void gemm_direct(
    const short* __restrict__ A, const short* __restrict__ B,
    float* __restrict__ out) {
  const int tid  = threadIdx.x;          // 0..255
  const int lane = tid & 63;
  const int wid  = tid >> 6;             // 0..3
  const int wm   = wid >> 1;             // 0..1  (64-row half of 128)
  const int wn   = wid & 1;              // 0..1  (128-col half of 256)
  const int bid = ((blockIdx.x & 7) << 6) | (blockIdx.x >> 3);  // T1 bijective
  const int mp = bid >> 4;               // 0..31
  const int np = bid & 15;               // 0..15

  // wave-constant fragment bases (element units); frag offsets are
  // (kt*8 + mi*2 + kk)*512 for A, (kt*16 + nj*2 + kk)*512 for B.
  const short* Ab = A + ((size_t)(mp * 256 + wm * 4) << 9) + lane * 8;
  const short* Bb = B + ((size_t)(np * 512 + wn * 8) << 9) + lane * 8;

  f32x16 acc[2][4];
#pragma unroll
  for (int i = 0; i < 2; ++i)
#pragma unroll
    for (int j = 0; j < 4; ++j)
#pragma unroll
      for (int e = 0; e < 16; ++e) acc[i][j][e] = 0.f;

  bf16x8 a0[2][2], b0[4][2], a1[2][2], b1[4][2];

#define LDA(dst, kt) do {                                                      \
    _Pragma("unroll")                                                          \
    for (int mi = 0; mi < 2; ++mi)                                             \
      _Pragma("unroll")                                                        \
      for (int kk = 0; kk < 2; ++kk)                                           \
        dst[mi][kk] = *(const bf16x8*)(Ab + (((kt) * 8 + mi * 2 + kk) << 9));  \
  } while (0)
#define LDB(dst, kt) do {                                                      \
    _Pragma("unroll")                                                          \
    for (int nj = 0; nj < 4; ++nj)                                             \
      _Pragma("unroll")                                                        \
      for (int kk = 0; kk < 2; ++kk)                                           \
        dst[nj][kk] = *(const bf16x8*)(Bb + (((kt) * 16 + nj * 2 + kk) << 9)); \
  } while (0)
#define MM(aa, bb) do {                                                        \
    __builtin_amdgcn_s_setprio(1);                                             \
    _Pragma("unroll")                                                          \
    for (int kk = 0; kk < 2; ++kk)                                             \
      _Pragma("unroll")                                                        \
      for (int mi = 0; mi < 2; ++mi)                                           \
        _Pragma("unroll")                                                      \
        for (int nj = 0; nj < 4; ++nj)                                         \
          acc[mi][nj] = __builtin_amdgcn_mfma_f32_32x32x16_bf16(               \
              aa[mi][kk], bb[nj][kk], acc[mi][nj], 0, 0, 0);                   \
    __builtin_amdgcn_s_setprio(0);                                             \
  } while (0)

  // prologue: tile 0 into buf0
  LDA(a0, 0); LDB(b0, 0);

  for (int kt = 0; kt < 30; kt += 2) {
    LDA(a1, kt + 1); LDB(b1, kt + 1);   // issue next tile
    MM(a0, b0);                          // compute current (waits its loads)
    LDA(a0, kt + 2); LDB(b0, kt + 2);
    MM(a1, b1);
  }
  // tail: kt = 30, 31
  LDA(a1, 31); LDB(b1, 31);
  MM(a0, b0);
  MM(a1, b1);

  // epilogue: out[n*4096+m]; C map (verified m74/m101/R12):
  // col(n)=lane&31, row(m)=(reg&3)+8*(reg>>2)+4*(lane>>5)
#pragma unroll
  for (int mi = 0; mi < 2; ++mi)
#pragma unroll
    for (int nj = 0; nj < 4; ++nj) {
      const int mb = mp * 128 + wm * 64 + mi * 32 + ((lane >> 5) << 2);
      const int nb = np * 256 + wn * 128 + nj * 32 + (lane & 31);
      const f32x16 c = acc[mi][nj];
#pragma unroll
      for (int q = 0; q < 4; ++q) {
        f32x4 v = {c[q * 4], c[q * 4 + 1], c[q * 4 + 2], c[q * 4 + 3]};
        *(f32x4*)(out + (size_t)nb * 4096 + mb + 8 * q) = v;
      }
    }
#undef LDA
#undef LDB
#undef MM
}

// ---------- launcher ----------
// setup_inputs order: 0:x 1:qweight_V 2:qzeros_V 3:scales_V 4:g_idx_V
//                     5:qweight_U 6:qzeros_U 7:scales_U 8:g_idx_U 9:S
extern "C" void kernel_launch(void* const* d_in, const int* in_sizes, int n_in,
                              void* d_out, int out_size, void* d_ws, size_t ws_size,
                              hipStream_t stream) {
  const int*   qw_V = (const int*)d_in[1];
  const int*   qz_V = (const int*)d_in[2];
  const float* sc_V = (const float*)d_in[3];
  const int*   qw_U = (const int*)d_in[5];
  const int*   qz_U = (const int*)d_in[6];
  const float* sc_U = (const float*)d_in[7];
  const float* S    = (const float*)d_in[9];

  short* A = (short*)d_ws;                  // 8 MB fragment-major (V*S)
  short* B = (short*)d_ws + 4096 * 1024;    // 8 MB fragment-major U^T
  float* out = (float*)d_out;

  dequant_fused<<<4096, 256, 0, stream>>>(qw_V, qz_V, sc_V, S, A,
                                          qw_U, qz_U, sc_U, B);
  gemm_direct<<<512, 256, 0, stream>>>(A, B, out);
}

// Round 15
// 52.148 us; speedup vs baseline: 1.2331x; 1.2331x over previous
//
#include <hip/hip_runtime.h>

// ---------- types ----------
typedef __attribute__((ext_vector_type(8))) short bf16x8;
typedef __attribute__((ext_vector_type(4))) float f32x4;

__device__ __forceinline__ short f2bf(float f) {
  unsigned u = __builtin_bit_cast(unsigned, f);
  u += 0x7fffu + ((u >> 16) & 1u);   // round-to-nearest-even
  return (short)(u >> 16);
}

// ---------- layout (16x16x32 fragment-major, verified R5/R11) ----------
// IN=4096, OUT=4096, RANK=1024, GROUP=128, PACK=8
// GEMM: out[n*4096+m] = sum_r W_V(m,r)*S(r) * W_U(r,n)
// A: elem addr = ((mp*32+kt)*8  + i)*512 + lane*8 + e   (i = 16-row frag 0..7)
//   m = mp*128 + i*16 + (lane&15); r = kt*32 + (lane>>4)*8 + e
// B: elem addr = ((np*32+kt)*16 + j)*512 + lane*8 + e   (j = 16-col frag 0..15)
//   n = np*256 + j*16 + (lane&15); r = kt*32 + (lane>>4)*8 + e
// Each 1 KB block = one MFMA fragment in lane order: GLL copies contiguously,
// ds_read_b128 stride-1 across lanes (conflict-free).

// ---------- stage 1: fused dequant (V -> A, U -> B) — R11 verbatim ----------
__global__ __launch_bounds__(256) void dequant_fused(
    const int* __restrict__ qw_V, const int* __restrict__ qz_V,
    const float* __restrict__ sc_V, const float* __restrict__ S,
    short* __restrict__ A,
    const int* __restrict__ qw_U, const int* __restrict__ qz_U,
    const float* __restrict__ sc_U, short* __restrict__ B) {
  const int bid = blockIdx.x;
  if (bid < 2048) {
    const int t    = bid * 256 + threadIdx.x;      // 0..524287
    const int tile = t >> 9;                       // mp*32 + kt
    const int blk  = (t >> 6) & 7;                 // i
    const int lane = t & 63;
    const int m  = (tile >> 5) * 128 + blk * 16 + (lane & 15);
    const int r0 = (tile & 31) * 32 + ((lane >> 4) << 3);
    const int g  = m >> 7;
    const int sh = (m & 7) << 2;
    const int zw = qz_V[(g << 7) + (r0 >> 3)];
    const int*   wq  = qw_V + (m >> 3) * 1024 + r0;
    const float* scp = sc_V + (g << 10) + r0;
    const float* sp  = S + r0;
    bf16x8 res;
#pragma unroll
    for (int e = 0; e < 8; ++e) {
      int q = (wq[e] >> sh) & 15;
      int z = ((zw >> (e << 2)) & 15) + 1;
      res[e] = f2bf((float)(q - z) * scp[e] * sp[e]);
    }
    *(bf16x8*)(A + ((size_t)t << 3)) = res;        // coalesced
  } else {
    const int t    = (bid - 2048) * 256 + threadIdx.x;
    const int tile = t >> 10;                      // np*32 + kt
    const int blk  = (t >> 6) & 15;                // j
    const int lane = t & 63;
    const int n  = (tile >> 5) * 256 + blk * 16 + (lane & 15);
    const int r0 = (tile & 31) * 32 + ((lane >> 4) << 3);
    const int w  = qw_U[(r0 >> 3) * 4096 + n];
    const int g  = r0 >> 7;
    const int zw = qz_U[(g << 9) + (n >> 3)];
    const int z  = ((zw >> ((n & 7) << 2)) & 15) + 1;
    const float s = sc_U[(g << 12) + n];
    bf16x8 res;
#pragma unroll
    for (int e = 0; e < 8; ++e) {
      int q = (w >> (e << 2)) & 15;
      res[e] = f2bf((float)(q - z) * s);
    }
    *(bf16x8*)(B + ((size_t)t << 3)) = res;
  }
}

// ---------- stage 2: 128x256, BK=32, 4 waves of 64x128, 2 blocks/CU ----------
// LDS: buf b at b*24576: A tile (8 KB) at +0, B tile (16 KB) at +8192; 48 KB
// total -> 2 blocks/CU. Wave tile 64(m) x 128(n): A dup 2x, B dup 2x ->
// LDS reads 48 KB/step (vs R11's 64), writes 24 KB. acc[4][8] f32x4 = 128 VGPR.
// Per K-step: 6 GLL staging, 12 ds_read_b128, 32 MFMA 16x16x32 per wave.
// vmcnt ledger (R11's, scaled to 6): prologue STAGE(0,1)=12 -> vmcnt(6) =
// tile0 landed. Steady kt: reads; lgkm(0); BAR (reads of buf done);
// STAGE(kt+2) into same buf; MFMA; vmcnt(6) retires tile kt+1; BAR (publish).
// kt==30: vmcnt(0). kt==31: no stage/wait.
#define GLL(g, l)                                                              \
  __builtin_amdgcn_global_load_lds(                                            \
      (const __attribute__((address_space(1))) void*)(g),                      \
      (__attribute__((address_space(3))) void*)(l), 16, 0, 0)

__global__ __launch_bounds__(256, 2) void gemm128x256(
    const short* __restrict__ A, const short* __restrict__ B,
    float* __restrict__ out) {
  __shared__ __align__(16) char lds[49152];   // 2 bufs x 24 KB -> 2 blocks/CU
  const int tid  = threadIdx.x;          // 0..255
  const int lane = tid & 63;
  const int wid  = tid >> 6;             // 0..3
  const int wm   = wid >> 1;             // 0..1  (64-row half of 128)
  const int wn   = wid & 1;              // 0..1  (128-col half of 256)
  const int bid = ((blockIdx.x & 7) << 6) | (blockIdx.x >> 3);  // T1 bijective
  const int mp = bid >> 4;               // 0..31
  const int np = bid & 15;               // 0..15

  // staging sources (per-lane tid*16B spans 4 KB); LDS dests wave-uniform
  const short* gAp = A + (size_t)mp * 131072 + tid * 8;  // panel = 32 tiles * 4096 elems
  const short* gBp = B + (size_t)np * 262144 + tid * 8;  // panel = 32 tiles * 8192 elems

#define STAGE(kt) do {                                                         \
    const int bo_ = ((kt) & 1) * 24576;                                        \
    const size_t ga_ = (size_t)(kt) * 4096;                                    \
    const size_t gb_ = (size_t)(kt) * 8192;                                    \
    GLL(gAp + ga_,        lds + bo_ +         (wid << 10));                    \
    GLL(gAp + ga_ + 2048, lds + bo_ + 4096 +  (wid << 10));                    \
    GLL(gBp + gb_,        lds + bo_ + 8192 +  (wid << 10));                    \
    GLL(gBp + gb_ + 2048, lds + bo_ + 12288 + (wid << 10));                    \
    GLL(gBp + gb_ + 4096, lds + bo_ + 16384 + (wid << 10));                    \
    GLL(gBp + gb_ + 6144, lds + bo_ + 20480 + (wid << 10));                    \
  } while (0)

  // fragment read bases: A frag f at f*1024; B frag f at 8192 + f*1024
  const char* Ard = lds + (lane << 4);
  const char* Brd = lds + 8192 + (lane << 4);

  f32x4 acc[4][8];
#pragma unroll
  for (int i = 0; i < 4; ++i)
#pragma unroll
    for (int j = 0; j < 8; ++j) acc[i][j] = f32x4{0.f, 0.f, 0.f, 0.f};

  // ---- prologue ----
  STAGE(0);
  STAGE(1);
  asm volatile("s_waitcnt vmcnt(6)" ::: "memory");
  __builtin_amdgcn_s_barrier();

  for (int kt = 0; kt < 32; ++kt) {
    const int bo = (kt & 1) * 24576;
    bf16x8 a[4], b[8];
#pragma unroll
    for (int i = 0; i < 4; ++i)
      a[i] = *(const bf16x8*)(Ard + bo + (((wm << 2) + i) << 10));
#pragma unroll
    for (int j = 0; j < 8; ++j)
      b[j] = *(const bf16x8*)(Brd + bo + (((wn << 3) + j) << 10));
    asm volatile("s_waitcnt lgkmcnt(0)" ::: "memory");
    __builtin_amdgcn_sched_barrier(0);
    __builtin_amdgcn_s_barrier();        // all waves' reads of this buf done
    if (kt < 30) STAGE(kt + 2);          // overwrite now-safe buf
    __builtin_amdgcn_s_setprio(1);
#pragma unroll
    for (int i = 0; i < 4; ++i)
#pragma unroll
      for (int j = 0; j < 8; ++j)
        acc[i][j] = __builtin_amdgcn_mfma_f32_16x16x32_bf16(
            a[i], b[j], acc[i][j], 0, 0, 0);
    __builtin_amdgcn_s_setprio(0);
    if (kt < 30)       asm volatile("s_waitcnt vmcnt(6)" ::: "memory");
    else if (kt == 30) asm volatile("s_waitcnt vmcnt(0)" ::: "memory");
    if (kt < 31) __builtin_amdgcn_s_barrier();   // publish tile kt+1
  }

  // epilogue: out[n*4096 + m]; C map (verified): col(n)=lane&15,
  // row(m)=(lane>>4)*4 + reg -> 4 regs = consecutive m -> float4 store
  const int mbase = (mp << 7) + (wm << 6) + ((lane >> 4) << 2);
  const int nbase = (np << 8) + (wn << 7) + (lane & 15);
#pragma unroll
  for (int i = 0; i < 4; ++i)
#pragma unroll
    for (int j = 0; j < 8; ++j)
      *(f32x4*)(out + (size_t)(nbase + j * 16) * 4096 + mbase + i * 16) =
          acc[i][j];
#undef STAGE
}

// ---------- launcher ----------
// setup_inputs order: 0:x 1:qweight_V 2:qzeros_V 3:scales_V 4:g_idx_V
//                     5:qweight_U 6:qzeros_U 7:scales_U 8:g_idx_U 9:S
extern "C" void kernel_launch(void* const* d_in, const int* in_sizes, int n_in,
                              void* d_out, int out_size, void* d_ws, size_t ws_size,
                              hipStream_t stream) {
  const int*   qw_V = (const int*)d_in[1];
  const int*   qz_V = (const int*)d_in[2];
  const float* sc_V = (const float*)d_in[3];
  const int*   qw_U = (const int*)d_in[5];
  const int*   qz_U = (const int*)d_in[6];
  const float* sc_U = (const float*)d_in[7];
  const float* S    = (const float*)d_in[9];

  short* A = (short*)d_ws;                  // 8 MB fragment-major (V*S)
  short* B = (short*)d_ws + 4096 * 1024;    // 8 MB fragment-major U^T
  float* out = (float*)d_out;

  dequant_fused<<<4096, 256, 0, stream>>>(qw_V, qz_V, sc_V, S, A,
                                          qw_U, qz_U, sc_U, B);
  gemm128x256<<<512, 256, 0, stream>>>(A, B, out);
}

// Round 16
// 50.139 us; speedup vs baseline: 1.2825x; 1.0401x over previous
//
#include <hip/hip_runtime.h>

// ---------- types ----------
typedef __attribute__((ext_vector_type(8))) short bf16x8;
typedef __attribute__((ext_vector_type(4))) float f32x4;

__device__ __forceinline__ short f2bf(float f) {
  unsigned u = __builtin_bit_cast(unsigned, f);
  u += 0x7fffu + ((u >> 16) & 1u);   // round-to-nearest-even
  return (short)(u >> 16);
}

// ---------- layout (16x16x32 fragment-major, verified R5/R11) ----------
// IN=4096, OUT=4096, RANK=1024, GROUP=128, PACK=8
// GEMM: out[n*4096+m] = sum_r W_V(m,r)*S(r) * W_U(r,n)
// A: elem addr = ((mp*32+kt)*8  + i)*512 + lane*8 + e   (i = 16-row frag 0..7)
//   m = mp*128 + i*16 + (lane&15); r = kt*32 + (lane>>4)*8 + e
// B: elem addr = ((np*32+kt)*16 + j)*512 + lane*8 + e   (j = 16-col frag 0..15)
//   n = np*256 + j*16 + (lane&15); r = kt*32 + (lane>>4)*8 + e
// Each 1 KB block = one MFMA fragment in lane order: GLL copies contiguously,
// ds_read_b128 stride-1 across lanes (conflict-free).

// ---------- stage 1: fused dequant (V -> A, U -> B) ----------
__global__ __launch_bounds__(256) void dequant_fused(
    const int* __restrict__ qw_V, const int* __restrict__ qz_V,
    const float* __restrict__ sc_V, const float* __restrict__ S,
    short* __restrict__ A,
    const int* __restrict__ qw_U, const int* __restrict__ qz_U,
    const float* __restrict__ sc_U, short* __restrict__ B) {
  const int bid = blockIdx.x;
  if (bid < 2048) {
    const int t    = bid * 256 + threadIdx.x;      // 0..524287
    const int tile = t >> 9;                       // mp*32 + kt
    const int blk  = (t >> 6) & 7;                 // i
    const int lane = t & 63;
    const int m  = (tile >> 5) * 128 + blk * 16 + (lane & 15);
    const int r0 = (tile & 31) * 32 + ((lane >> 4) << 3);
    const int g  = m >> 7;
    const int sh = (m & 7) << 2;
    const int zw = qz_V[(g << 7) + (r0 >> 3)];
    const int*   wq  = qw_V + (m >> 3) * 1024 + r0;
    const float* scp = sc_V + (g << 10) + r0;
    const float* sp  = S + r0;
    bf16x8 res;
#pragma unroll
    for (int e = 0; e < 8; ++e) {
      int q = (wq[e] >> sh) & 15;
      int z = ((zw >> (e << 2)) & 15) + 1;
      res[e] = f2bf((float)(q - z) * scp[e] * sp[e]);
    }
    *(bf16x8*)(A + ((size_t)t << 3)) = res;        // coalesced
  } else {
    const int t    = (bid - 2048) * 256 + threadIdx.x;
    const int tile = t >> 10;                      // np*32 + kt
    const int blk  = (t >> 6) & 15;                // j
    const int lane = t & 63;
    const int n  = (tile >> 5) * 256 + blk * 16 + (lane & 15);
    const int r0 = (tile & 31) * 32 + ((lane >> 4) << 3);
    const int w  = qw_U[(r0 >> 3) * 4096 + n];
    const int g  = r0 >> 7;
    const int zw = qz_U[(g << 9) + (n >> 3)];
    const int z  = ((zw >> ((n & 7) << 2)) & 15) + 1;
    const float s = sc_U[(g << 12) + n];
    bf16x8 res;
#pragma unroll
    for (int e = 0; e < 8; ++e) {
      int q = (w >> (e << 2)) & 15;
      res[e] = f2bf((float)(q - z) * s);
    }
    *(bf16x8*)(B + ((size_t)t << 3)) = res;
  }
}

// ---------- stage 2: 128x256, BK=32, 8 waves, 2 blocks/CU (best: R11) ------
// LDS: buf b at b*24576: A tile (8 KB) at +0, B tile (16 KB) at +8192.
// 48 KB total -> 2 blocks/CU co-resident (512 blocks / 256 CU): cross-block
// TLP hides barriers, vmcnt waits, prologue fill, and the fp32 epilogue tail.
// Per K-step: 3 GLL staging, 8 ds_read_b128, 16 MFMA 16x16x32 per wave.
// vmcnt ledger: prologue stages t0,t1 (6 GLL) -> vmcnt(3) = t0 landed.
// Steady iter kt: reads; lgkm(0); BAR (all reads of buf done); STAGE(kt+2)
// into same buf (now safe); 16 MFMA; vmcnt(3) retires tile kt+1; BAR.
// kt==30: no stage, vmcnt(0). kt==31: no stage, no wait.
#define GLL(g, l)                                                              \
  __builtin_amdgcn_global_load_lds(                                            \
      (const __attribute__((address_space(1))) void*)(g),                      \
      (__attribute__((address_space(3))) void*)(l), 16, 0, 0)

__global__ __launch_bounds__(512, 4) void gemm128x256(
    const short* __restrict__ A, const short* __restrict__ B,
    float* __restrict__ out) {
  __shared__ __align__(16) char lds[49152];
  const int tid  = threadIdx.x;          // 0..511
  const int lane = tid & 63;
  const int wid  = tid >> 6;             // 0..7
  const int wm   = wid >> 2;             // 0..1  (64-row half of 128)
  const int wn   = wid & 3;              // 0..3  (64-col quarter of 256)
  const int bid = ((blockIdx.x & 7) << 6) | (blockIdx.x >> 3);  // T1 bijective
  const int mp = bid >> 4;               // 0..31
  const int np = bid & 15;               // 0..15

  // staging sources (per-lane tid*16B); LDS dests wave-uniform
  const short* gAp = A + (size_t)mp * 131072 + tid * 8;  // panel = 32 tiles * 4096 elems
  const short* gBp = B + (size_t)np * 262144 + tid * 8;  // panel = 32 tiles * 8192 elems
  char* const ldsA = lds + (wid << 10);
  char* const ldsB = lds + 8192 + (wid << 10);

#define STAGE(kt) do {                                                         \
    const int bo_ = ((kt) & 1) * 24576;                                        \
    GLL(gAp + (size_t)(kt) * 4096,        ldsA + bo_);                         \
    GLL(gBp + (size_t)(kt) * 8192,        ldsB + bo_);                         \
    GLL(gBp + (size_t)(kt) * 8192 + 4096, ldsB + bo_ + 8192);                  \
  } while (0)

  // fragment read bases
  const char* Ard = lds + (lane << 4);           // + buf + (wm*4+i)*1024
  const char* Brd = lds + 8192 + (lane << 4);    // + buf + (wn*4+j)*1024

  f32x4 acc[4][4];
#pragma unroll
  for (int i = 0; i < 4; ++i)
#pragma unroll
    for (int j = 0; j < 4; ++j) acc[i][j] = f32x4{0.f, 0.f, 0.f, 0.f};

  // ---- prologue ----
  STAGE(0);
  STAGE(1);
  asm volatile("s_waitcnt vmcnt(3)" ::: "memory");
  __builtin_amdgcn_s_barrier();

  for (int kt = 0; kt < 32; ++kt) {
    const int bo = (kt & 1) * 24576;
    bf16x8 a[4], b[4];
#pragma unroll
    for (int i = 0; i < 4; ++i)
      a[i] = *(const bf16x8*)(Ard + bo + ((wm << 2) + i) * 1024);
#pragma unroll
    for (int j = 0; j < 4; ++j)
      b[j] = *(const bf16x8*)(Brd + bo + ((wn << 2) + j) * 1024);
    asm volatile("s_waitcnt lgkmcnt(0)" ::: "memory");
    __builtin_amdgcn_sched_barrier(0);
    __builtin_amdgcn_s_barrier();        // all waves' reads of this buf done
    if (kt < 30) STAGE(kt + 2);          // overwrite now-safe buf
    __builtin_amdgcn_s_setprio(1);
#pragma unroll
    for (int i = 0; i < 4; ++i)
#pragma unroll
      for (int j = 0; j < 4; ++j)
        acc[i][j] = __builtin_amdgcn_mfma_f32_16x16x32_bf16(
            a[i], b[j], acc[i][j], 0, 0, 0);
    __builtin_amdgcn_s_setprio(0);
    if (kt < 30)       asm volatile("s_waitcnt vmcnt(3)" ::: "memory");
    else if (kt == 30) asm volatile("s_waitcnt vmcnt(0)" ::: "memory");
    if (kt < 31) __builtin_amdgcn_s_barrier();   // publish tile kt+1
  }

  // epilogue: out[n*4096 + m]; 4 acc regs = consecutive m -> float4 store
  const int mbase = (mp << 7) + (wm << 6) + ((lane >> 4) << 2);
  const int nbase = (np << 8) + (wn << 6) + (lane & 15);
#pragma unroll
  for (int mi = 0; mi < 4; ++mi)
#pragma unroll
    for (int ni = 0; ni < 4; ++ni)
      *(f32x4*)(out + (size_t)(nbase + ni * 16) * 4096 + mbase + mi * 16) =
          acc[mi][ni];
#undef STAGE
}

// ---------- launcher ----------
// setup_inputs order: 0:x 1:qweight_V 2:qzeros_V 3:scales_V 4:g_idx_V
//                     5:qweight_U 6:qzeros_U 7:scales_U 8:g_idx_U 9:S
extern "C" void kernel_launch(void* const* d_in, const int* in_sizes, int n_in,
                              void* d_out, int out_size, void* d_ws, size_t ws_size,
                              hipStream_t stream) {
  const int*   qw_V = (const int*)d_in[1];
  const int*   qz_V = (const int*)d_in[2];
  const float* sc_V = (const float*)d_in[3];
  const int*   qw_U = (const int*)d_in[5];
  const int*   qz_U = (const int*)d_in[6];
  const float* sc_U = (const float*)d_in[7];
  const float* S    = (const float*)d_in[9];

  short* A = (short*)d_ws;                  // 8 MB fragment-major (V*S)
  short* B = (short*)d_ws + 4096 * 1024;    // 8 MB fragment-major U^T
  float* out = (float*)d_out;

  dequant_fused<<<4096, 256, 0, stream>>>(qw_V, qz_V, sc_V, S, A,
                                          qw_U, qz_U, sc_U, B);
  gemm128x256<<<512, 512, 0, stream>>>(A, B, out);
}